// Round 5
// baseline (657.645 us; speedup 1.0000x reference)
//
#include <hip/hip_runtime.h>
#include <hip/hip_bf16.h>

#define B_ 128
#define E_ 512
#define H_ 1024
#define S_ 514
#define NEGV -1000000.0f

typedef __attribute__((ext_vector_type(8))) short bf16x8;
typedef __attribute__((ext_vector_type(4))) short s16x4;
typedef __attribute__((ext_vector_type(4))) float f32x4;

typedef __attribute__((address_space(1))) const void* gptr_t;
typedef __attribute__((address_space(3))) void* lptr_t;

__device__ __forceinline__ short f2bf(float f) {
  unsigned u = __builtin_bit_cast(unsigned, f);
  return (short)((u + 0x8000u) >> 16);
}

__device__ __forceinline__ float gelu_f(float x) {
  return 0.5f * x * (1.0f + erff(x * 0.7071067811865475f));
}

// ---------------- convert keys f32 -> bf16 (memory-bound pass)
__global__ void convert_keys(const float* __restrict__ in, short* __restrict__ out) {
  size_t total = (size_t)B_ * E_ * H_;
  size_t stride = (size_t)gridDim.x * blockDim.x * 8;
  for (size_t i = ((size_t)blockIdx.x * blockDim.x + threadIdx.x) * 8; i < total; i += stride) {
    f32x4 a = *(const f32x4*)(in + i);
    f32x4 b = *(const f32x4*)(in + i + 4);
    bf16x8 v;
    v[0] = f2bf(a[0]); v[1] = f2bf(a[1]); v[2] = f2bf(a[2]); v[3] = f2bf(a[3]);
    v[4] = f2bf(b[0]); v[5] = f2bf(b[1]); v[6] = f2bf(b[2]); v[7] = f2bf(b[3]);
    *(bf16x8*)(out + i) = v;
  }
}

// ---------------- prep: Q1[b,h] = query_b @ W1q + b1 ; N1 = null@W1k ; A1 = new@W1k
__global__ void prep_q1(const float* __restrict__ query, const float* __restrict__ W1,
                        const float* __restrict__ b1, const float* __restrict__ nulla,
                        const float* __restrict__ newa, float* __restrict__ Q1,
                        float* __restrict__ N1, float* __restrict__ A1) {
  __shared__ float vec[H_];
  int bid = blockIdx.x;            // 0..519
  int rowIdx = bid >> 2;           // 0..129
  int h = (bid & 3) * 256 + threadIdx.x;
  const float* src;
  int woff;
  if (rowIdx < B_)      { src = query + (size_t)rowIdx * H_; woff = 0; }
  else if (rowIdx == B_){ src = nulla; woff = H_; }
  else                  { src = newa;  woff = H_; }
  for (int i = threadIdx.x; i < H_; i += 256) vec[i] = src[i];
  __syncthreads();
  float acc = (rowIdx < B_) ? b1[h] : 0.f;
  const float* wp = W1 + (size_t)woff * H_ + h;
  #pragma unroll 8
  for (int d = 0; d < H_; ++d) acc += vec[d] * wp[(size_t)d * H_];
  if (rowIdx < B_)       Q1[rowIdx * H_ + h] = acc;
  else if (rowIdx == B_) N1[h] = acc;
  else                   A1[h] = acc;
}

// ---------------- prep: w1kT[n][k] = bf16(W1[H+k][n])
__global__ void transpose_w1k(const float* __restrict__ W1, short* __restrict__ w1kT) {
  __shared__ float tb[64][65];
  int k0 = (blockIdx.x & 15) * 64;
  int n0 = (blockIdx.x >> 4) * 64;
  int x = threadIdx.x & 63;
  int ty = threadIdx.x >> 6;  // 0..3
  #pragma unroll
  for (int i = 0; i < 16; ++i) {
    int row = i * 4 + ty;  // k_local
    tb[row][x] = W1[(size_t)(H_ + k0 + row) * H_ + n0 + x];
  }
  __syncthreads();
  #pragma unroll
  for (int i = 0; i < 16; ++i) {
    int row = i * 4 + ty;  // n_local
    w1kT[(size_t)(n0 + row) * H_ + k0 + x] = f2bf(tb[x][row]);
  }
}

// ---------------- base scores: b2 +/- mention + mask, plus full null/new slots
__global__ void finalize_base(const int* __restrict__ es, const float* __restrict__ mention,
                              const float* __restrict__ W2, const float* __restrict__ b2,
                              const float* __restrict__ Q1, const float* __restrict__ N1,
                              const float* __restrict__ A1, float* __restrict__ scores) {
  int b = blockIdx.x;
  int t = threadIdx.x;
  float b2v = b2[0], mv = mention[b];
  int esz = es[b];
  for (int s = t; s < S_; s += 256) {
    float base = b2v + (s == 0 ? -mv : mv);
    if (s >= esz + 1 && s <= E_) base += NEGV;
    scores[b * S_ + s] = base;
  }
  float sum0 = 0.f, sum1 = 0.f;
  for (int h = t; h < H_; h += 256) {
    float q = Q1[b * H_ + h], w = W2[h];
    sum0 += gelu_f(q + N1[h]) * w;
    sum1 += gelu_f(q + A1[h]) * w;
  }
  #pragma unroll
  for (int m = 32; m > 0; m >>= 1) { sum0 += __shfl_xor(sum0, m); sum1 += __shfl_xor(sum1, m); }
  __shared__ float red0[4], red1[4];
  int lanei = t & 63, wdi = t >> 6;
  if (lanei == 0) { red0[wdi] = sum0; red1[wdi] = sum1; }
  __syncthreads();
  if (t == 0) {
    scores[b * S_ + 0]      += red0[0] + red0[1] + red0[2] + red0[3];
    scores[b * S_ + S_ - 1] += red1[0] + red1[1] + red1[2] + red1[3];
  }
}

// ================ PRIMARY: bf16 GEMM, m97 structure (global_load_lds + XOR swizzle)
// A = keysBf [65536][1024] bf16, B = w1kT [1024][1024] bf16, both row-major-in-K.
#define GBM 128
#define GBN 128
#define GBK 64

__global__ __launch_bounds__(256, 2) void gemm_bf16(
    const short* __restrict__ A, const short* __restrict__ Bm,
    const float* __restrict__ Q1, const float* __restrict__ W2,
    float* __restrict__ scores) {
  __shared__ short As[GBM * GBK];  // 16 KB, linear (global_load_lds dest)
  __shared__ short Bs[GBN * GBK];  // 16 KB

  int bid = blockIdx.x;
  int cpx = gridDim.x >> 3;   // 4096/8 = 512, bijective XCD swizzle
  bid = (bid & 7) * cpx + (bid >> 3);
  int tileM = bid >> 3;
  int tileN = bid & 7;
  int row0 = tileM * GBM;
  int col0 = tileN * GBN;

  int t = threadIdx.x;
  int lane = t & 63;
  int wid = t >> 6;
  int wr = wid >> 1, wc = wid & 1;
  int l15 = lane & 15, lHi = lane >> 4;

  // staging: wave wid owns chunks c = wid*4+i (i=0..3) of each 16KB tile.
  // chunk c = rows c*8..c*8+7 (8 rows x 128B). LDS dest linear: chunkBase + lane*16.
  // inverse-swizzled global source: lane l -> row c*8 + (l>>3), colByte ((l&7)^(l>>3))<<4.
  int srcRow = lane >> 3;                               // 0..7 within chunk
  int srcColE = ((lane & 7) ^ (lane >> 3)) << 3;        // element offset (x8 bf16 = 16B)
  const short* aSrc = A + (size_t)(row0 + wid * 32 + srcRow) * H_ + srcColE;
  const short* bSrc = Bm + (size_t)(col0 + wid * 32 + srcRow) * H_ + srcColE;
  short* aDst = As + (wid * 4) * 512;   // 512 shorts = 1 KB per chunk
  short* bDst = Bs + (wid * 4) * 512;

  f32x4 acc[4][4];
  #pragma unroll
  for (int m = 0; m < 4; ++m)
    #pragma unroll
    for (int n = 0; n < 4; ++n) acc[m][n] = (f32x4){0.f, 0.f, 0.f, 0.f};

  // read addressing (byte): row = base + m*16 + l15, col = (kk*64 + lHi*16) ^ ((l15&7)<<4)
  int swz = (l15 & 7) << 4;
  const char* aRd = (const char*)As + (wr * 64 + l15) * 128;
  const char* bRd = (const char*)Bs + (wc * 64 + l15) * 128;

  for (int k0 = 0; k0 < H_; k0 += GBK) {
    __syncthreads();
    #pragma unroll
    for (int i = 0; i < 4; ++i) {
      __builtin_amdgcn_global_load_lds((gptr_t)(aSrc + (size_t)i * 8 * H_ + k0),
                                       (lptr_t)(aDst + i * 512), 16, 0, 0);
      __builtin_amdgcn_global_load_lds((gptr_t)(bSrc + (size_t)i * 8 * H_ + k0),
                                       (lptr_t)(bDst + i * 512), 16, 0, 0);
    }
    __syncthreads();  // compiler emits vmcnt(0) drain before barrier
    #pragma unroll
    for (int kk = 0; kk < 2; ++kk) {
      bf16x8 af[4], bv[4];
      #pragma unroll
      for (int m = 0; m < 4; ++m)
        af[m] = *(const bf16x8*)(aRd + m * 2048 + (((kk << 6) | (lHi << 4)) ^ swz));
      #pragma unroll
      for (int n = 0; n < 4; ++n)
        bv[n] = *(const bf16x8*)(bRd + n * 2048 + (((kk << 6) | (lHi << 4)) ^ swz));
      #pragma unroll
      for (int m = 0; m < 4; ++m)
        #pragma unroll
        for (int n = 0; n < 4; ++n)
          acc[m][n] = __builtin_amdgcn_mfma_f32_16x16x32_bf16(af[m], bv[n], acc[m][n], 0, 0, 0);
    }
  }

  // epilogue: pre = acc + Q1[b,col]; score_part[row] = sum_col gelu(pre)*W2[col]
  int bIdx = row0 >> 9;
  float q1v[4], w2v[4];
  #pragma unroll
  for (int n = 0; n < 4; ++n) {
    int col = col0 + wc * 64 + n * 16 + l15;
    q1v[n] = Q1[bIdx * H_ + col];
    w2v[n] = W2[col];
  }
  #pragma unroll
  for (int m = 0; m < 4; ++m) {
    float part[4] = {0.f, 0.f, 0.f, 0.f};
    #pragma unroll
    for (int n = 0; n < 4; ++n)
      #pragma unroll
      for (int i = 0; i < 4; ++i)
        part[i] += gelu_f(acc[m][n][i] + q1v[n]) * w2v[n];
    #pragma unroll
    for (int i = 0; i < 4; ++i) {
      float v = part[i];
      v += __shfl_xor(v, 1);
      v += __shfl_xor(v, 2);
      v += __shfl_xor(v, 4);
      v += __shfl_xor(v, 8);
      if (l15 == 0) {
        int row = row0 + wr * 64 + m * 16 + lHi * 4 + i;
        int s = (row & 511) + 1;
        atomicAdd(&scores[bIdx * S_ + s], v);
      }
    }
  }
}

// ================ FALLBACK (small ws): round-1 reg-staged f32 GEMM (known-good)
#define BM 128
#define BN 128
#define BK 64
#define LDT 72

__global__ __launch_bounds__(256, 2) void gemm_f32reg(
    const float* __restrict__ keys, const short* __restrict__ w1kT,
    const float* __restrict__ Q1, const float* __restrict__ W2,
    float* __restrict__ scores) {
  __shared__ short As[BM * LDT];
  __shared__ short Bs[BN * LDT];

  int bid = blockIdx.x;
  int cpx = gridDim.x >> 3;
  bid = (bid & 7) * cpx + (bid >> 3);
  int tileM = bid >> 3;
  int tileN = bid & 7;
  int row0 = tileM * BM;
  int col0 = tileN * BN;

  int t = threadIdx.x;
  int lane = t & 63;
  int wid = t >> 6;
  int wr = wid >> 1, wc = wid & 1;
  int l15 = lane & 15, lHi = lane >> 4;

  int asr = t >> 4;
  int asc = (t & 15) * 4;
  int bsr = t >> 3;
  int bsc = (t & 7) * 8;

  const float* aBase = keys + (size_t)(row0 + asr) * H_ + asc;
  const short* bBase = w1kT + (size_t)(col0 + bsr) * H_ + bsc;

  f32x4 aReg[8];
  bf16x8 bReg[4];
  f32x4 acc[4][4];
  #pragma unroll
  for (int m = 0; m < 4; ++m)
    #pragma unroll
    for (int n = 0; n < 4; ++n) acc[m][n] = (f32x4){0.f, 0.f, 0.f, 0.f};

  #pragma unroll
  for (int p = 0; p < 8; ++p) aReg[p] = *(const f32x4*)(aBase + (size_t)p * 16 * H_);
  #pragma unroll
  for (int p = 0; p < 4; ++p) bReg[p] = *(const bf16x8*)(bBase + (size_t)p * 32 * H_);

  for (int k0 = 0; k0 < H_; k0 += BK) {
    __syncthreads();
    #pragma unroll
    for (int p = 0; p < 8; ++p) {
      s16x4 v;
      #pragma unroll
      for (int j = 0; j < 4; ++j) v[j] = f2bf(aReg[p][j]);
      *(s16x4*)&As[(p * 16 + asr) * LDT + asc] = v;
    }
    #pragma unroll
    for (int p = 0; p < 4; ++p)
      *(bf16x8*)&Bs[(p * 32 + bsr) * LDT + bsc] = bReg[p];
    __syncthreads();
    if (k0 + BK < H_) {
      #pragma unroll
      for (int p = 0; p < 8; ++p) aReg[p] = *(const f32x4*)(aBase + (size_t)p * 16 * H_ + k0 + BK);
      #pragma unroll
      for (int p = 0; p < 4; ++p) bReg[p] = *(const bf16x8*)(bBase + (size_t)p * 32 * H_ + k0 + BK);
    }
    #pragma unroll
    for (int kk = 0; kk < 2; ++kk) {
      bf16x8 af[4], bfv[4];
      #pragma unroll
      for (int m = 0; m < 4; ++m)
        af[m] = *(const bf16x8*)&As[(wr * 64 + m * 16 + l15) * LDT + kk * 32 + lHi * 8];
      #pragma unroll
      for (int n = 0; n < 4; ++n)
        bfv[n] = *(const bf16x8*)&Bs[(wc * 64 + n * 16 + l15) * LDT + kk * 32 + lHi * 8];
      #pragma unroll
      for (int m = 0; m < 4; ++m)
        #pragma unroll
        for (int n = 0; n < 4; ++n)
          acc[m][n] = __builtin_amdgcn_mfma_f32_16x16x32_bf16(af[m], bfv[n], acc[m][n], 0, 0, 0);
    }
  }

  int bIdx = row0 >> 9;
  float q1v[4], w2v[4];
  #pragma unroll
  for (int n = 0; n < 4; ++n) {
    int col = col0 + wc * 64 + n * 16 + l15;
    q1v[n] = Q1[bIdx * H_ + col];
    w2v[n] = W2[col];
  }
  #pragma unroll
  for (int m = 0; m < 4; ++m) {
    float part[4] = {0.f, 0.f, 0.f, 0.f};
    #pragma unroll
    for (int n = 0; n < 4; ++n)
      #pragma unroll
      for (int i = 0; i < 4; ++i)
        part[i] += gelu_f(acc[m][n][i] + q1v[n]) * w2v[n];
    #pragma unroll
    for (int i = 0; i < 4; ++i) {
      float v = part[i];
      v += __shfl_xor(v, 1);
      v += __shfl_xor(v, 2);
      v += __shfl_xor(v, 4);
      v += __shfl_xor(v, 8);
      if (l15 == 0) {
        int row = row0 + wr * 64 + m * 16 + lHi * 4 + i;
        int s = (row & 511) + 1;
        atomicAdd(&scores[bIdx * S_ + s], v);
      }
    }
  }
}

extern "C" void kernel_launch(void* const* d_in, const int* in_sizes, int n_in,
                              void* d_out, int out_size, void* d_ws, size_t ws_size,
                              hipStream_t stream) {
  const float* query   = (const float*)d_in[0];
  const float* keys    = (const float*)d_in[1];
  const int*   esz     = (const int*)d_in[2];
  const float* mention = (const float*)d_in[3];
  const float* W1      = (const float*)d_in[4];
  const float* b1      = (const float*)d_in[5];
  const float* W2      = (const float*)d_in[6];
  const float* b2      = (const float*)d_in[7];
  const float* nulla   = (const float*)d_in[8];
  const float* newa    = (const float*)d_in[9];
  float* scores = (float*)d_out;

  const size_t keysBfBytes = (size_t)B_ * E_ * H_ * 2;   // 128 MB
  const size_t w1kTBytes   = (size_t)H_ * H_ * 2;        // 2 MB
  const size_t q1Bytes     = (size_t)B_ * H_ * 4;        // 512 KB
  const size_t needPrimary = keysBfBytes + w1kTBytes + q1Bytes + 2 * H_ * 4;

  if (ws_size >= needPrimary) {
    short* keysBf = (short*)d_ws;
    short* w1kT   = (short*)((char*)d_ws + keysBfBytes);
    float* Q1     = (float*)((char*)d_ws + keysBfBytes + w1kTBytes);
    float* N1     = Q1 + (size_t)B_ * H_;
    float* A1     = N1 + H_;

    convert_keys<<<8192, 256, 0, stream>>>(keys, keysBf);
    prep_q1<<<520, 256, 0, stream>>>(query, W1, b1, nulla, newa, Q1, N1, A1);
    transpose_w1k<<<256, 256, 0, stream>>>(W1, w1kT);
    finalize_base<<<B_, 256, 0, stream>>>(esz, mention, W2, b2, Q1, N1, A1, scores);
    gemm_bf16<<<4096, 256, 0, stream>>>(keysBf, w1kT, Q1, W2, scores);
  } else {
    short* w1kT = (short*)d_ws;
    float* Q1   = (float*)((char*)d_ws + w1kTBytes);
    float* N1   = Q1 + (size_t)B_ * H_;
    float* A1   = N1 + H_;

    prep_q1<<<520, 256, 0, stream>>>(query, W1, b1, nulla, newa, Q1, N1, A1);
    transpose_w1k<<<256, 256, 0, stream>>>(W1, w1kT);
    finalize_base<<<B_, 256, 0, stream>>>(esz, mention, W2, b2, Q1, N1, A1, scores);
    gemm_f32reg<<<4096, 256, 0, stream>>>(keys, w1kT, Q1, W2, scores);
  }
}

// Round 8
// 643.836 us; speedup vs baseline: 1.0214x; 1.0214x over previous
//
#include <hip/hip_runtime.h>
#include <hip/hip_bf16.h>

#define B_ 128
#define E_ 512
#define H_ 1024
#define S_ 514
#define NEGV -1000000.0f

typedef __attribute__((ext_vector_type(8))) short bf16x8;
typedef __attribute__((ext_vector_type(4))) short s16x4;
typedef __attribute__((ext_vector_type(4))) float f32x4;

typedef __attribute__((address_space(1))) const void* gptr_t;
typedef __attribute__((address_space(3))) void* lptr_t;

__device__ __forceinline__ short f2bf(float f) {
  unsigned u = __builtin_bit_cast(unsigned, f);
  return (short)((u + 0x8000u) >> 16);
}

__device__ __forceinline__ float gelu_f(float x) {
  return 0.5f * x * (1.0f + erff(x * 0.7071067811865475f));
}

// ---------------- init: Q1 rows = b1 (broadcast), N1 = A1 = 0
__global__ void init_q1(const float* __restrict__ b1, float* __restrict__ Q1,
                        float* __restrict__ N1, float* __restrict__ A1) {
  int b = blockIdx.x;          // 0..129
  int t = threadIdx.x;         // 0..255, 4 floats each
  if (b < B_) {
    f32x4 v = *(const f32x4*)(b1 + t * 4);
    *(f32x4*)(Q1 + (size_t)b * H_ + t * 4) = v;
  } else if (b == B_) {
    *(f32x4*)(N1 + t * 4) = (f32x4){0.f, 0.f, 0.f, 0.f};
  } else {
    *(f32x4*)(A1 + t * 4) = (f32x4){0.f, 0.f, 0.f, 0.f};
  }
}

// ---------------- prep2: Q1 += query @ W1q ; N1 += null @ W1k ; A1 += new @ W1k
// block = (rowGroup of 8, d-chunk of 64). One W1 f32x4 load feeds 8x4 FMAs
// (independent accumulators -> no dependent chain, high compute:load ratio).
#define RPB 8
__global__ void prep2(const float* __restrict__ query, const float* __restrict__ W1,
                      const float* __restrict__ nulla, const float* __restrict__ newa,
                      float* __restrict__ Q1, float* __restrict__ N1, float* __restrict__ A1) {
  int bid = blockIdx.x;        // 17 rowGroups * 16 dchunks = 272
  int rg = bid >> 4;           // 0..16 (16 = special group: null,new)
  int dc = bid & 15;           // 64 d's each
  int t = threadIdx.x;
  bool special = (rg == 16);
  int woff = special ? H_ : 0;

  __shared__ float vec[RPB][64];
  {
    int r = t >> 6, dd = t & 63;   // 256 threads cover 4 rows; loop twice
    #pragma unroll
    for (int rr = 0; rr < 2; ++rr) {
      int row = r + rr * 4;
      float v = 0.f;
      if (!special) v = query[(size_t)(rg * RPB + row) * H_ + dc * 64 + dd];
      else if (row == 0) v = nulla[dc * 64 + dd];
      else if (row == 1) v = newa[dc * 64 + dd];
      vec[row][dd] = v;            // special rows >=2 stay 0 -> contribute nothing
    }
  }
  __syncthreads();

  const float* wp = W1 + (size_t)(woff + dc * 64) * H_ + t * 4;
  f32x4 acc[RPB];
  #pragma unroll
  for (int r = 0; r < RPB; ++r) acc[r] = (f32x4){0.f, 0.f, 0.f, 0.f};

  #pragma unroll 4
  for (int dd = 0; dd < 64; ++dd) {
    f32x4 w = *(const f32x4*)(wp + (size_t)dd * H_);
    #pragma unroll
    for (int r = 0; r < RPB; ++r) {
      float v = vec[r][dd];
      acc[r][0] += v * w[0]; acc[r][1] += v * w[1];
      acc[r][2] += v * w[2]; acc[r][3] += v * w[3];
    }
  }

  if (!special) {
    #pragma unroll
    for (int r = 0; r < RPB; ++r) {
      float* dst = Q1 + (size_t)(rg * RPB + r) * H_ + t * 4;
      atomicAdd(dst + 0, acc[r][0]); atomicAdd(dst + 1, acc[r][1]);
      atomicAdd(dst + 2, acc[r][2]); atomicAdd(dst + 3, acc[r][3]);
    }
  } else {
    float* d0 = N1 + t * 4;
    atomicAdd(d0 + 0, acc[0][0]); atomicAdd(d0 + 1, acc[0][1]);
    atomicAdd(d0 + 2, acc[0][2]); atomicAdd(d0 + 3, acc[0][3]);
    float* d1 = A1 + t * 4;
    atomicAdd(d1 + 0, acc[1][0]); atomicAdd(d1 + 1, acc[1][1]);
    atomicAdd(d1 + 2, acc[1][2]); atomicAdd(d1 + 3, acc[1][3]);
  }
}

// ---------------- prep: w1kT[n][k] = bf16(W1[H+k][n])
__global__ void transpose_w1k(const float* __restrict__ W1, short* __restrict__ w1kT) {
  __shared__ float tb[64][65];
  int k0 = (blockIdx.x & 15) * 64;
  int n0 = (blockIdx.x >> 4) * 64;
  int x = threadIdx.x & 63;
  int ty = threadIdx.x >> 6;  // 0..3
  #pragma unroll
  for (int i = 0; i < 16; ++i) {
    int row = i * 4 + ty;  // k_local
    tb[row][x] = W1[(size_t)(H_ + k0 + row) * H_ + n0 + x];
  }
  __syncthreads();
  #pragma unroll
  for (int i = 0; i < 16; ++i) {
    int row = i * 4 + ty;  // n_local
    w1kT[(size_t)(n0 + row) * H_ + k0 + x] = f2bf(tb[x][row]);
  }
}

// ---------------- base scores: b2 +/- mention + mask, plus full null/new slots
__global__ void finalize_base(const int* __restrict__ es, const float* __restrict__ mention,
                              const float* __restrict__ W2, const float* __restrict__ b2,
                              const float* __restrict__ Q1, const float* __restrict__ N1,
                              const float* __restrict__ A1, float* __restrict__ scores) {
  int b = blockIdx.x;
  int t = threadIdx.x;
  float b2v = b2[0], mv = mention[b];
  int esz = es[b];
  for (int s = t; s < S_; s += 256) {
    float base = b2v + (s == 0 ? -mv : mv);
    if (s >= esz + 1 && s <= E_) base += NEGV;
    scores[b * S_ + s] = base;
  }
  float sum0 = 0.f, sum1 = 0.f;
  for (int h = t; h < H_; h += 256) {
    float q = Q1[b * H_ + h], w = W2[h];
    sum0 += gelu_f(q + N1[h]) * w;
    sum1 += gelu_f(q + A1[h]) * w;
  }
  #pragma unroll
  for (int m = 32; m > 0; m >>= 1) { sum0 += __shfl_xor(sum0, m); sum1 += __shfl_xor(sum1, m); }
  __shared__ float red0[4], red1[4];
  int lanei = t & 63, wdi = t >> 6;
  if (lanei == 0) { red0[wdi] = sum0; red1[wdi] = sum1; }
  __syncthreads();
  if (t == 0) {
    scores[b * S_ + 0]      += red0[0] + red0[1] + red0[2] + red0[3];
    scores[b * S_ + S_ - 1] += red1[0] + red1[1] + red1[2] + red1[3];
  }
}

// ================ GEMM (keys f32 read directly; cvt fused into A staging)
// A: reg-stage f32 -> bf16 -> swizzled ds_write (same content layout round-5 reads expect)
// B: global_load_lds linear dest + inverse-swizzled source (unchanged, proven 0-conflict)
#define GBM 128
#define GBN 128
#define GBK 64

__global__ __launch_bounds__(256, 2) void gemm_fused(
    const float* __restrict__ keys, const short* __restrict__ Bm,
    const float* __restrict__ Q1, const float* __restrict__ W2,
    float* __restrict__ scores) {
  __shared__ short As[GBM * GBK];  // 16 KB, swizzled content
  __shared__ short Bs[GBN * GBK];  // 16 KB, linear dest (read with XOR)

  int bid = blockIdx.x;
  int cpx = gridDim.x >> 3;   // 4096/8 = 512, bijective XCD swizzle
  bid = (bid & 7) * cpx + (bid >> 3);
  int tileM = bid >> 3;
  int tileN = bid & 7;
  int row0 = tileM * GBM;
  int col0 = tileN * GBN;

  int t = threadIdx.x;
  int lane = t & 63;
  int wid = t >> 6;
  int wr = wid >> 1, wc = wid & 1;
  int l15 = lane & 15, lHi = lane >> 4;

  // ---- A staging (reg path): rows p*16+asr, k-elems asc..asc+3
  int asr = t >> 4;            // 0..15
  int asc = (t & 15) * 4;      // 0..60
  const float* aBase = keys + (size_t)(row0 + asr) * H_ + asc;
  // swizzled ds_write byte offset within row: ((t&15)*8) ^ ((asr&7)<<4)
  char* aWr = (char*)As + asr * 128 + ((((t & 15) * 8)) ^ ((asr & 7) << 4));

  // ---- B staging (global_load_lds): identical to round-5 validated path
  int srcRow = lane >> 3;
  int srcColE = ((lane & 7) ^ (lane >> 3)) << 3;
  const short* bSrc = Bm + (size_t)(col0 + wid * 32 + srcRow) * H_ + srcColE;
  short* bDst = Bs + (wid * 4) * 512;

  f32x4 aReg[8];
  f32x4 acc[4][4];
  #pragma unroll
  for (int m = 0; m < 4; ++m)
    #pragma unroll
    for (int n = 0; n < 4; ++n) acc[m][n] = (f32x4){0.f, 0.f, 0.f, 0.f};

  #pragma unroll
  for (int p = 0; p < 8; ++p) aReg[p] = *(const f32x4*)(aBase + (size_t)p * 16 * H_);

  int swz = (l15 & 7) << 4;
  const char* aRd = (const char*)As + (wr * 64 + l15) * 128;
  const char* bRd = (const char*)Bs + (wc * 64 + l15) * 128;

  for (int k0 = 0; k0 < H_; k0 += GBK) {
    __syncthreads();
    // A: cvt + swizzled write
    #pragma unroll
    for (int p = 0; p < 8; ++p) {
      s16x4 v;
      #pragma unroll
      for (int j = 0; j < 4; ++j) v[j] = f2bf(aReg[p][j]);
      *(s16x4*)(aWr + p * 2048) = v;   // row stride 16*128B = 2048B
    }
    // B: direct-to-LDS
    #pragma unroll
    for (int i = 0; i < 4; ++i)
      __builtin_amdgcn_global_load_lds((gptr_t)(bSrc + (size_t)i * 8 * H_ + k0),
                                       (lptr_t)(bDst + i * 512), 16, 0, 0);
    __syncthreads();  // drains lgkm (A writes) + vmcnt (B loads)
    if (k0 + GBK < H_) {  // prefetch next A slab; hides under MFMA
      #pragma unroll
      for (int p = 0; p < 8; ++p)
        aReg[p] = *(const f32x4*)(aBase + (size_t)p * 16 * H_ + k0 + GBK);
    }
    #pragma unroll
    for (int kk = 0; kk < 2; ++kk) {
      bf16x8 af[4], bv[4];
      #pragma unroll
      for (int m = 0; m < 4; ++m)
        af[m] = *(const bf16x8*)(aRd + m * 2048 + (((kk << 6) | (lHi << 4)) ^ swz));
      #pragma unroll
      for (int n = 0; n < 4; ++n)
        bv[n] = *(const bf16x8*)(bRd + n * 2048 + (((kk << 6) | (lHi << 4)) ^ swz));
      #pragma unroll
      for (int m = 0; m < 4; ++m)
        #pragma unroll
        for (int n = 0; n < 4; ++n)
          acc[m][n] = __builtin_amdgcn_mfma_f32_16x16x32_bf16(af[m], bv[n], acc[m][n], 0, 0, 0);
    }
  }

  // epilogue: pre = acc + Q1[b,col]; score_part[row] = sum_col gelu(pre)*W2[col]
  int bIdx = row0 >> 9;
  float q1v[4], w2v[4];
  #pragma unroll
  for (int n = 0; n < 4; ++n) {
    int col = col0 + wc * 64 + n * 16 + l15;
    q1v[n] = Q1[bIdx * H_ + col];
    w2v[n] = W2[col];
  }
  #pragma unroll
  for (int m = 0; m < 4; ++m) {
    float part[4] = {0.f, 0.f, 0.f, 0.f};
    #pragma unroll
    for (int n = 0; n < 4; ++n)
      #pragma unroll
      for (int i = 0; i < 4; ++i)
        part[i] += gelu_f(acc[m][n][i] + q1v[n]) * w2v[n];
    #pragma unroll
    for (int i = 0; i < 4; ++i) {
      float v = part[i];
      v += __shfl_xor(v, 1);
      v += __shfl_xor(v, 2);
      v += __shfl_xor(v, 4);
      v += __shfl_xor(v, 8);
      if (l15 == 0) {
        int row = row0 + wr * 64 + m * 16 + lHi * 4 + i;
        int s = (row & 511) + 1;
        atomicAdd(&scores[bIdx * S_ + s], v);
      }
    }
  }
}

extern "C" void kernel_launch(void* const* d_in, const int* in_sizes, int n_in,
                              void* d_out, int out_size, void* d_ws, size_t ws_size,
                              hipStream_t stream) {
  const float* query   = (const float*)d_in[0];
  const float* keys    = (const float*)d_in[1];
  const int*   esz     = (const int*)d_in[2];
  const float* mention = (const float*)d_in[3];
  const float* W1      = (const float*)d_in[4];
  const float* b1      = (const float*)d_in[5];
  const float* W2      = (const float*)d_in[6];
  const float* b2      = (const float*)d_in[7];
  const float* nulla   = (const float*)d_in[8];
  const float* newa    = (const float*)d_in[9];
  float* scores = (float*)d_out;

  const size_t w1kTBytes = (size_t)H_ * H_ * 2;   // 2 MB
  short* w1kT = (short*)d_ws;
  float* Q1   = (float*)((char*)d_ws + w1kTBytes);
  float* N1   = Q1 + (size_t)B_ * H_;
  float* A1   = N1 + H_;

  init_q1<<<130, 256, 0, stream>>>(b1, Q1, N1, A1);
  prep2<<<272, 256, 0, stream>>>(query, W1, nulla, newa, Q1, N1, A1);
  transpose_w1k<<<256, 256, 0, stream>>>(W1, w1kT);
  finalize_base<<<B_, 256, 0, stream>>>(esz, mention, W2, b2, Q1, N1, A1, scores);
  gemm_fused<<<4096, 256, 0, stream>>>(keys, w1kT, Q1, W2, scores);
}